// Round 3
// baseline (1633.800 us; speedup 1.0000x reference)
//
#include <hip/hip_runtime.h>

typedef unsigned short u16;
typedef unsigned int u32;
typedef u16 u16x4 __attribute__((ext_vector_type(4)));
typedef u16 u16x8 __attribute__((ext_vector_type(8)));
typedef u32 u32x4 __attribute__((ext_vector_type(4)));
typedef __bf16 bf16x8 __attribute__((ext_vector_type(8)));
typedef float f32x4 __attribute__((ext_vector_type(4)));

#define NB   2
#define NQH  32
#define NKH  8
#define SEQ  2048
#define DIM  128
#define BKV  64   // kv keys per tile
#define QT   64   // q rows per block (16 per wave)

__device__ __forceinline__ u16 f2bf(float f) {
  u32 u = __builtin_bit_cast(u32, f);
  u += 0x7FFFu + ((u >> 16) & 1u);   // round-to-nearest-even
  return (u16)(u >> 16);
}
__device__ __forceinline__ u32 pack2(float a, float b) {
  return (u32)f2bf(a) | ((u32)f2bf(b) << 16);
}

__device__ __forceinline__ f32x4 mfma16(u16x8 a, u16x8 b, f32x4 c) {
  return __builtin_amdgcn_mfma_f32_16x16x32_bf16(
      __builtin_bit_cast(bf16x8, a), __builtin_bit_cast(bf16x8, b), c, 0, 0, 0);
}

// swizzled LDS address: byte ^= (row&7)<<4  (keeps 16B granules intact)
__device__ __forceinline__ u16* lds_at(u16* base, int row, int col, int rowBytes) {
  int byte = row * rowBytes + col * 2;
  byte ^= (row & 7) << 4;
  return (u16*)((char*)base + byte);
}

__global__ __launch_bounds__(256, 4) void gqa_fwd(
    const float* __restrict__ Qg, const float* __restrict__ Kg,
    const float* __restrict__ Vg, float* __restrict__ Og) {
  __shared__ __align__(16) u16 ldsK[BKV * DIM];    // [64][128] bf16, swizzled
  __shared__ __align__(16) u16 ldsVT[DIM * BKV];   // [128][64] bf16 (V^T, key-permuted), swizzled

  const int tid  = threadIdx.x;
  const int lane = tid & 63;
  const int wave = tid >> 6;
  const int lr   = lane & 15;   // q-row within 16 (and MFMA row/col index)
  const int lg   = lane >> 4;   // group 0..3

  const int qtile = blockIdx.x;          // 0..31
  const int bqh   = blockIdx.y;          // 0..63
  const int b     = bqh / NQH;
  const int qh    = bqh % NQH;
  const int kh    = qh / (NQH / NKH);

  const size_t qbase = (size_t)bqh * SEQ * DIM;
  const size_t kbase = (size_t)(b * NKH + kh) * SEQ * DIM;

  const int qrow0 = qtile * QT + wave * 16;
  const float scale = 0.08838834764831845f;  // 1/sqrt(128)

  // preload Q fragments (scale folded in); B-operand layout: Q[q=lr][d=32s+8lg+e]
  u16x8 qf[4];
  #pragma unroll
  for (int s = 0; s < 4; ++s) {
    const float* qp = Qg + qbase + (size_t)(qrow0 + lr) * DIM + 32 * s + 8 * lg;
    float4 a = *(const float4*)qp;
    float4 c = *(const float4*)(qp + 4);
    u16x8 v = { f2bf(a.x * scale), f2bf(a.y * scale), f2bf(a.z * scale), f2bf(a.w * scale),
                f2bf(c.x * scale), f2bf(c.y * scale), f2bf(c.z * scale), f2bf(c.w * scale) };
    qf[s] = v;
  }

  const f32x4 zero4 = {0.f, 0.f, 0.f, 0.f};
  f32x4 oacc[8];
  #pragma unroll
  for (int dt = 0; dt < 8; ++dt) oacc[dt] = zero4;
  float mrow = -1e30f;   // running max for q-row lr
  float lrow = 0.0f;     // running denom for q-row lr

  const int b8  = tid & 7;       // lane within 8-lane transpose group
  const int grp = tid >> 3;      // 0..31

  for (int kt = 0; kt < SEQ / BKV; ++kt) {
    __syncthreads();   // previous tile's LDS reads done before overwrite
    {
      // ---- stage K tile: coalesced float4 reads, conflict-free swizzled writes
      const float* src = Kg + kbase + (size_t)kt * BKV * DIM;
      #pragma unroll
      for (int u = 0; u < 8; ++u) {
        int c  = tid + 256 * u;        // 0..2047 float4-chunks
        int j  = c >> 5;               // key row 0..63
        int dm = (c & 31) * 4;         // d offset
        float4 v = *(const float4*)(src + j * DIM + dm);
        u16x4 w = { f2bf(v.x), f2bf(v.y), f2bf(v.z), f2bf(v.w) };
        *(u16x4*)lds_at(ldsK, j, dm, 2 * DIM) = w;
      }
      // ---- stage V^T (key-permuted): 8x8 in-register transpose per 8-lane group
      // slot(ks, kw) holds key sigma = 32ks + 16*((kw&7)>>2) + 4*(kw>>3) + (kw&3)
      const float* vsrc = Vg + kbase + (size_t)kt * BKV * DIM;
      #pragma unroll
      for (int it = 0; it < 4; ++it) {
        int bi = 32 * it + grp;        // block id, 0..127
        int vlg = bi & 3;              // k-group (lg of consumers)
        int vks = (bi >> 2) & 1;       // 32-block
        int vdb = bi >> 3;             // d block 0..15
        int d0  = vdb * 8;
        int kbase8 = 32 * vks + 4 * vlg;
        // lane b8 loads key row kbase8 + 16*(b8>>2) + (b8&3)
        int krow = kbase8 + 16 * (b8 >> 2) + (b8 & 3);
        const float* p0 = vsrc + (size_t)krow * DIM + d0;
        float4 v0 = *(const float4*)(p0);
        float4 v1 = *(const float4*)(p0 + 4);
        float x[8] = {v0.x, v0.y, v0.z, v0.w, v1.x, v1.y, v1.z, v1.w};
        // butterfly transpose: after this, x[r] = V[keyrow(r)][d0+b8]
        #pragma unroll
        for (int i = 0; i < 3; ++i) {
          const int s = 1 << i;
          const bool hi = (b8 & s) != 0;
          #pragma unroll
          for (int c0 = 0; c0 < 8; ++c0) {
            if (c0 & s) continue;
            const int c1 = c0 | s;
            float send = hi ? x[c0] : x[c1];
            float recv = __shfl_xor(send, s, 64);
            if (hi) x[c0] = recv; else x[c1] = recv;
          }
        }
        u16x8 w;
        #pragma unroll
        for (int r = 0; r < 8; ++r) w[r] = f2bf(x[r]);
        // write slots 32*vks + 8*vlg + (0..7) at row d0+b8
        *(u16x8*)lds_at(ldsVT, d0 + b8, 32 * vks + 8 * vlg, 2 * BKV) = w;
      }
    }
    __syncthreads();

    // ---- ST = K Q^T (swapped): sacc[jt][e] = S[q=lr][key=16jt+4lg+e]
    f32x4 sacc[4];
    #pragma unroll
    for (int jt = 0; jt < 4; ++jt) sacc[jt] = zero4;
    #pragma unroll
    for (int jt = 0; jt < 4; ++jt) {
      #pragma unroll
      for (int s = 0; s < 4; ++s) {
        u16x8 kf = *(const u16x8*)lds_at(ldsK, jt * 16 + lr, 32 * s + 8 * lg, 2 * DIM);
        sacc[jt] = mfma16(kf, qf[s], sacc[jt]);
      }
    }

    // ---- online softmax, fully in-register (q-row = lr per lane)
    float tmax = sacc[0][0];
    #pragma unroll
    for (int jt = 0; jt < 4; ++jt)
      #pragma unroll
      for (int e = 0; e < 4; ++e) tmax = fmaxf(tmax, sacc[jt][e]);
    tmax = fmaxf(tmax, __shfl_xor(tmax, 16, 64));
    tmax = fmaxf(tmax, __shfl_xor(tmax, 32, 64));
    float mn   = fmaxf(mrow, tmax);
    float corr = __expf(mrow - mn);
    mrow = mn;

    u32 pk[8];   // pk[2jt+(e>>1)]: P[q=lr][key=16jt+4lg+e], halfword e&1
    float rsum = 0.f;
    #pragma unroll
    for (int jt = 0; jt < 4; ++jt) {
      float p0 = __expf(sacc[jt][0] - mn);
      float p1 = __expf(sacc[jt][1] - mn);
      float p2 = __expf(sacc[jt][2] - mn);
      float p3 = __expf(sacc[jt][3] - mn);
      rsum += (p0 + p1) + (p2 + p3);
      pk[2 * jt]     = pack2(p0, p1);
      pk[2 * jt + 1] = pack2(p2, p3);
    }
    rsum += __shfl_xor(rsum, 16, 64);
    rsum += __shfl_xor(rsum, 32, 64);
    lrow = lrow * corr + rsum;

    // rescale O (rows q = 4lg+e): fetch corr for those rows
    float corr_o[4];
    #pragma unroll
    for (int e = 0; e < 4; ++e) corr_o[e] = __shfl(corr, 4 * lg + e, 64);
    #pragma unroll
    for (int dt = 0; dt < 8; ++dt) {
      #pragma unroll
      for (int e = 0; e < 4; ++e) oacc[dt][e] *= corr_o[e];
    }

    // ---- A-frag for PV is a pure bitcast of pk (k-permutation folded into V^T):
    // af[ks][kw] = P[q=lr][sigma(ks, 8lg+kw')] with sigma matching ldsVT slots.
    u16x8 af[2];
    af[0] = __builtin_bit_cast(u16x8, u32x4{pk[0], pk[1], pk[2], pk[3]});
    af[1] = __builtin_bit_cast(u16x8, u32x4{pk[4], pk[5], pk[6], pk[7]});

    // ---- O += P V : B-frag = ldsVT[d=16dt+lr][slot=32ks+8lg+e']
    #pragma unroll
    for (int dt = 0; dt < 8; ++dt) {
      #pragma unroll
      for (int ks = 0; ks < 2; ++ks) {
        u16x8 vf = *(const u16x8*)lds_at(ldsVT, dt * 16 + lr, 32 * ks + 8 * lg, 2 * BKV);
        oacc[dt] = mfma16(af[ks], vf, oacc[dt]);
      }
    }
  }

  // ---- epilogue: normalize and store (f32); O rows are q = 4lg+e
  float linv = 1.0f / lrow;
  float linv_o[4];
  #pragma unroll
  for (int e = 0; e < 4; ++e) linv_o[e] = __shfl(linv, 4 * lg + e, 64);
  #pragma unroll
  for (int e = 0; e < 4; ++e) {
    int row = qrow0 + 4 * lg + e;
    float* op = Og + qbase + (size_t)row * DIM;
    #pragma unroll
    for (int dt = 0; dt < 8; ++dt) op[dt * 16 + lr] = oacc[dt][e] * linv_o[e];
  }
}

extern "C" void kernel_launch(void* const* d_in, const int* in_sizes, int n_in,
                              void* d_out, int out_size, void* d_ws, size_t ws_size,
                              hipStream_t stream) {
  const float* Q = (const float*)d_in[0];
  const float* K = (const float*)d_in[1];
  const float* V = (const float*)d_in[2];
  float* O = (float*)d_out;
  dim3 grid(SEQ / QT, NB * NQH);
  gqa_fwd<<<grid, 256, 0, stream>>>(Q, K, V, O);
}

// Round 4
// 207.222 us; speedup vs baseline: 7.8843x; 7.8843x over previous
//
#include <hip/hip_runtime.h>

typedef unsigned short u16;
typedef unsigned int u32;
typedef u16 u16x4 __attribute__((ext_vector_type(4)));
typedef u16 u16x8 __attribute__((ext_vector_type(8)));
typedef u32 u32x4 __attribute__((ext_vector_type(4)));
typedef __bf16 bf16x8 __attribute__((ext_vector_type(8)));
typedef float f32x4 __attribute__((ext_vector_type(4)));

#define NB   2
#define NQH  32
#define NKH  8
#define SEQ  2048
#define DIM  128
#define BKV  64
#define QT   64
#define NTILE   (SEQ / BKV)          // 32
#define TILEU16 (BKV * DIM)          // 8192 u16 = 16KB per image tile
#define VOFFU16 (16 * NTILE * TILEU16) // V images after 16*(b,kh)*32 K tiles

__device__ __forceinline__ u16 f2bf(float f) {
  u32 u = __builtin_bit_cast(u32, f);
  u += 0x7FFFu + ((u >> 16) & 1u);
  return (u16)(u >> 16);
}
__device__ __forceinline__ u32 cvtpk(float lo, float hi) {
  u32 r;
  asm("v_cvt_pk_bf16_f32 %0, %1, %2" : "=v"(r) : "v"(lo), "v"(hi));
  return r;
}
__device__ __forceinline__ f32x4 mfma16(u16x8 a, u16x8 b, f32x4 c) {
  return __builtin_amdgcn_mfma_f32_16x16x32_bf16(
      __builtin_bit_cast(bf16x8, a), __builtin_bit_cast(bf16x8, b), c, 0, 0, 0);
}
// swizzled LDS read address in u16 units: idx = row*rowU16 + (col ^ ((row&7)<<3))
__device__ __forceinline__ const u16* lds_at(const u16* base, int row, int col, int rowU16) {
  return base + row * rowU16 + (col ^ ((row & 7) << 3));
}
__device__ __forceinline__ void gl_lds16(const u16* g, u16* l) {
  __builtin_amdgcn_global_load_lds(
      (const __attribute__((address_space(1))) u32*)(const void*)g,
      (__attribute__((address_space(3))) u32*)(void*)l, 16, 0, 0);
}

// ---- pre-pass: build swizzled bf16 LDS images of K and V^T(sigma-permuted) ----
// K image tile t=(bkh*32+kt): u16 idx j*128 + (dm ^ ((j&7)<<3)) = bf16 K[j][dm]
// V image tile: u16 idx d*64 + (8cc ^ ((d&7)<<3)) + i = bf16 V[key(8cc+i)][d],
//   key(s) = 32*(s>>5) + 4*((s>>3)&3) + 16*((s&7)>>2) + (s&3)   (verified sigma)
__global__ __launch_bounds__(256) void prep(const float* __restrict__ Kg,
                                            const float* __restrict__ Vg,
                                            u16* __restrict__ ws) {
  const int bid = blockIdx.x;          // 0..1023 : first 512 K, next 512 V
  const int tid = threadIdx.x;
  const int tile = bid & 511;          // bkh*32 + kt
  const size_t sbase = (size_t)(tile >> 5) * SEQ * DIM + (size_t)(tile & 31) * BKV * DIM;
  if (bid < 512) {
    const float* src = Kg + sbase;
    u16* img = ws + (size_t)tile * TILEU16;
    #pragma unroll
    for (int u = 0; u < 8; ++u) {
      int c = tid + 256 * u;           // float4 chunk 0..2047
      int j = c >> 5;
      int dm = (c & 31) * 4;
      float4 v = *(const float4*)(src + j * DIM + dm);
      u16x4 w = { f2bf(v.x), f2bf(v.y), f2bf(v.z), f2bf(v.w) };
      *(u16x4*)(img + j * 128 + (dm ^ ((j & 7) << 3))) = w;
    }
  } else {
    const float* src = Vg + sbase;
    u16* img = ws + VOFFU16 + (size_t)tile * TILEU16;
    #pragma unroll
    for (int u = 0; u < 4; ++u) {
      int c = tid + 256 * u;           // u16x8 chunk 0..1023
      int d = c >> 3;
      int cc = c & 7;
      u16x8 w;
      #pragma unroll
      for (int i = 0; i < 8; ++i) {
        int s = 8 * cc + i;
        int key = 32 * (s >> 5) + 4 * ((s >> 3) & 3) + 16 * (i >> 2) + (i & 3);
        w[i] = f2bf(src[key * DIM + d]);
      }
      *(u16x8*)(img + d * 64 + ((8 * cc) ^ ((d & 7) << 3))) = w;
    }
  }
}

__global__ __launch_bounds__(256) void gqa_fwd(const float* __restrict__ Qg,
                                               const u16* __restrict__ ws,
                                               float* __restrict__ Og) {
  __shared__ __align__(16) u16 ldsK[TILEU16];    // byte image of K tile
  __shared__ __align__(16) u16 ldsVT[TILEU16];   // byte image of V^T tile

  const int tid  = threadIdx.x;
  const int lane = tid & 63;
  const int wave = tid >> 6;
  const int lr   = lane & 15;
  const int lg   = lane >> 4;

  const int qtile = blockIdx.x;
  const int bqh   = blockIdx.y;
  const int b     = bqh / NQH;
  const int qh    = bqh % NQH;
  const int kh    = qh / (NQH / NKH);

  const size_t qbase = (size_t)bqh * SEQ * DIM;
  const u16* imgK = ws + (size_t)((b * NKH + kh) * NTILE) * TILEU16;
  const u16* imgV = imgK + VOFFU16;

  const int qrow0 = qtile * QT + wave * 16;
  const float scale = 0.08838834764831845f;  // 1/sqrt(128)

  // Q fragments (scale folded): qf[s] elem e = Q[q=lr][d=32s+8lg+e]
  u16x8 qf[4];
  #pragma unroll
  for (int s = 0; s < 4; ++s) {
    const float* qp = Qg + qbase + (size_t)(qrow0 + lr) * DIM + 32 * s + 8 * lg;
    float4 a = *(const float4*)qp;
    float4 c = *(const float4*)(qp + 4);
    qf[s] = __builtin_bit_cast(u16x8, u32x4{
        cvtpk(a.x * scale, a.y * scale), cvtpk(a.z * scale, a.w * scale),
        cvtpk(c.x * scale, c.y * scale), cvtpk(c.z * scale, c.w * scale) });
  }

  const f32x4 zero4 = {0.f, 0.f, 0.f, 0.f};
  f32x4 oacc[8];
  #pragma unroll
  for (int dt = 0; dt < 8; ++dt) oacc[dt] = zero4;
  float mrow = -1e30f, lrow = 0.0f;

  for (int kt = 0; kt < NTILE; ++kt) {
    __syncthreads();   // all waves done reading previous tile
    // ---- stage tile images via async global->LDS (linear byte copy)
    #pragma unroll
    for (int u = 0; u < 4; ++u) {
      const int q = u * 4 + wave;      // 1KB chunk 0..15
      gl_lds16(imgK + (size_t)kt * TILEU16 + q * 512 + lane * 8, &ldsK[q * 512]);
      gl_lds16(imgV + (size_t)kt * TILEU16 + q * 512 + lane * 8, &ldsVT[q * 512]);
    }
    asm volatile("s_waitcnt vmcnt(0)" ::: "memory");
    __syncthreads();

    // ---- ST = K Q^T (swapped): sacc[jt][e] = S[q=lr][key=16jt+4lg+e]
    f32x4 sacc[4];
    #pragma unroll
    for (int jt = 0; jt < 4; ++jt) sacc[jt] = zero4;
    #pragma unroll
    for (int jt = 0; jt < 4; ++jt) {
      #pragma unroll
      for (int s = 0; s < 4; ++s) {
        u16x8 kf = *(const u16x8*)lds_at(ldsK, jt * 16 + lr, 32 * s + 8 * lg, 128);
        sacc[jt] = mfma16(kf, qf[s], sacc[jt]);
      }
    }

    // ---- online softmax, in-register (q-row = lr per lane)
    float tmax = sacc[0][0];
    #pragma unroll
    for (int jt = 0; jt < 4; ++jt)
      #pragma unroll
      for (int e = 0; e < 4; ++e) tmax = fmaxf(tmax, sacc[jt][e]);
    tmax = fmaxf(tmax, __shfl_xor(tmax, 16, 64));
    tmax = fmaxf(tmax, __shfl_xor(tmax, 32, 64));

    // T13 defer-max: only rescale when the max moved by > 8
    if (!__all(tmax - mrow <= 8.0f)) {
      float mn = fmaxf(mrow, tmax);
      float corr = __expf(mrow - mn);
      mrow = mn;
      lrow *= corr;
      float corr_o[4];
      #pragma unroll
      for (int e = 0; e < 4; ++e) corr_o[e] = __shfl(corr, 4 * lg + e, 64);
      #pragma unroll
      for (int dt = 0; dt < 8; ++dt)
        #pragma unroll
        for (int e = 0; e < 4; ++e) oacc[dt][e] *= corr_o[e];
    }

    u32 pk[8];   // pk[2jt+h] = {P[key=16jt+4lg+2h], P[key=16jt+4lg+2h+1]}
    float rsum = 0.f;
    #pragma unroll
    for (int jt = 0; jt < 4; ++jt) {
      float p0 = __expf(sacc[jt][0] - mrow);
      float p1 = __expf(sacc[jt][1] - mrow);
      float p2 = __expf(sacc[jt][2] - mrow);
      float p3 = __expf(sacc[jt][3] - mrow);
      rsum += (p0 + p1) + (p2 + p3);
      pk[2 * jt]     = cvtpk(p0, p1);
      pk[2 * jt + 1] = cvtpk(p2, p3);
    }
    rsum += __shfl_xor(rsum, 16, 64);
    rsum += __shfl_xor(rsum, 32, 64);
    lrow += rsum;

    // ---- PV: A-frag is a pure bitcast of pk (sigma folded into V image)
    u16x8 af[2];
    af[0] = __builtin_bit_cast(u16x8, u32x4{pk[0], pk[1], pk[2], pk[3]});
    af[1] = __builtin_bit_cast(u16x8, u32x4{pk[4], pk[5], pk[6], pk[7]});
    #pragma unroll
    for (int dt = 0; dt < 8; ++dt) {
      #pragma unroll
      for (int ks = 0; ks < 2; ++ks) {
        u16x8 vf = *(const u16x8*)lds_at(ldsVT, dt * 16 + lr, 32 * ks + 8 * lg, 64);
        oacc[dt] = mfma16(af[ks], vf, oacc[dt]);
      }
    }
  }

  // ---- epilogue: normalize and store; O rows are q = 4lg+e
  float linv = 1.0f / lrow;
  float linv_o[4];
  #pragma unroll
  for (int e = 0; e < 4; ++e) linv_o[e] = __shfl(linv, 4 * lg + e, 64);
  #pragma unroll
  for (int e = 0; e < 4; ++e) {
    int row = qrow0 + 4 * lg + e;
    float* op = Og + qbase + (size_t)row * DIM;
    #pragma unroll
    for (int dt = 0; dt < 8; ++dt) op[dt * 16 + lr] = oacc[dt][e] * linv_o[e];
  }
}

extern "C" void kernel_launch(void* const* d_in, const int* in_sizes, int n_in,
                              void* d_out, int out_size, void* d_ws, size_t ws_size,
                              hipStream_t stream) {
  const float* Q = (const float*)d_in[0];
  const float* K = (const float*)d_in[1];
  const float* V = (const float*)d_in[2];
  float* O = (float*)d_out;
  u16* ws = (u16*)d_ws;
  prep<<<dim3(1024), 256, 0, stream>>>(K, V, ws);
  dim3 grid(SEQ / QT, NB * NQH);
  gqa_fwd<<<grid, 256, 0, stream>>>(Q, ws, O);
}